// Round 4
// baseline (877.251 us; speedup 1.0000x reference)
//
#include <hip/hip_runtime.h>

// StabilityPredictorSchnet: B=4, L=384, H=128, F=384
// One block per (b,l); KT=32 edge rows per iteration, NIT=12.
// R4: VALU-bound (302us busy) but 50% idle from phase-serial structure.
// (a) epi2(it-1) hoisted into G1(it) phase: register-only epilogue VALU
//     hides G1 mfma chain + staging-load latency. acc2 carried across iter.
// (b) ONE barrier/iter (was 2): double-buffered sA(2x8K)+sT1(2x24K)=64KB.
//     All cross-iter LDS hazards barrier-ordered or disjoint-buffer.
// (c) 3-term erf poly (A&S 7.1.25, err 2.5e-5 << bf16 rounding).
// Spill watch: WRITE_SIZE must stay ~21MB; >60MB => acc2 live range spilled.

#define Bz 4
#define Lz 384
#define Hz 128
#define Fz 384
#define KT 32          // k-tile rows (edge rows per iteration)
#define NIT 12         // 384 / KT

typedef short bf16x8 __attribute__((ext_vector_type(8)));
typedef float f32x4 __attribute__((ext_vector_type(4)));

__device__ __forceinline__ unsigned short f2bf(float f) {
  unsigned int u = __float_as_uint(f);
  u += 0x7FFFu + ((u >> 16) & 1u);   // RNE bf16
  return (unsigned short)(u >> 16);
}

// gelu(x) = 0.5x(1+erf(x/sqrt2)); erf via A&S 7.1.25 3-term (|err|<=2.5e-5)
__device__ __forceinline__ float gelu_f(float x) {
  const float a1 = 0.3480242f, a2 = -0.0958798f, a3 = 0.7478556f;
  float z = fabsf(x) * 0.7071067811865476f;
  float t = __builtin_amdgcn_rcpf(__builtin_fmaf(0.47047f, z, 1.0f));
  float poly = t * __builtin_fmaf(t, __builtin_fmaf(t, a3, a2), a1);
  float e = __builtin_fmaf(-poly, __expf(-z * z), 1.0f);
  return 0.5f * x * (1.0f + copysignf(e, x));
}

// ---- prep: zero acc/counter; pack fw1/fw2 into MFMA B-fragment order ----
__global__ __launch_bounds__(256) void prep_kernel(
    const float* __restrict__ fw1, const float* __restrict__ fw2,
    unsigned short* __restrict__ fw1P, unsigned short* __restrict__ fw2P,
    float* __restrict__ accbuf, int* __restrict__ ctr)
{
  int e = blockIdx.x * 256 + threadIdx.x;
  if (e < 16) accbuf[e] = 0.0f;
  if (e == 16) *ctr = 0;
  if (e < 24 * 4 * 64 * 8) {
    int j = e & 7, lf = (e >> 3) & 63, ks = (e >> 9) & 3, t = e >> 11;
    int n = t * 16 + (lf & 15);
    int k = ks * 32 + (lf >> 4) * 8 + j;
    fw1P[e] = f2bf(fw1[(size_t)k * Fz + n]);
  } else if (e < 24 * 4 * 64 * 8 + 24 * 12 * 64 * 8) {
    int o = e - 24 * 4 * 64 * 8;
    int j = o & 7, lf = (o >> 3) & 63, r = o >> 9;
    int ks = r % 12, t = r / 12;
    int n = t * 16 + (lf & 15);
    int k = ks * 32 + (lf >> 4) * 8 + j;
    fw2P[o] = f2bf(fw2[(size_t)k * Fz + n]);
  }
}

__global__ __launch_bounds__(512, 4) void schnet_main(
    const float* __restrict__ hV, const float* __restrict__ hE,
    const float* __restrict__ mask,
    const unsigned short* __restrict__ fw1P, const float* __restrict__ fb1,
    const unsigned short* __restrict__ fw2P, const float* __restrict__ fb2,
    const float* __restrict__ hw1, const float* __restrict__ hb1,
    const float* __restrict__ hw2, const float* __restrict__ hb2,
    const float* __restrict__ hw3, const float* __restrict__ hb3,
    float* __restrict__ accbuf, int* __restrict__ ctr,
    float* __restrict__ out)
{
  const int bl   = blockIdx.x;
  const int b    = bl / Lz;
  const int l    = bl - b * Lz;
  const int tid  = threadIdx.x;
  const int wave = tid >> 6;    // 0..7
  const int lane = tid & 63;
  const int lr   = lane & 15;
  const int quad = lane >> 4;   // 0..3
  const int l7   = lane & 7;

  // 64 KB: sA[2] @0/8K (8K each), sT1[2] @16K/40K (24K each).
  // Head-MLP buffers alias sA[0] after the loop (all sA[0] reads long done).
  __shared__ __attribute__((aligned(16))) char sMem[65536];
  float* sXC = (float*)sMem;           // 384 f
  float* sHp = sXC + Fz;               // 4*128 f
  float* sH1 = sHp + 4 * Hz;           // 128 f
  float* sH2 = sH1 + Hz;               // 64 f
  int*   sLast = (int*)(sH2 + 64);

  const float* hE_bl = hE + (size_t)bl * (Lz * Hz);
  const unsigned short* w1base = fw1P + (size_t)lane * 8;
  const unsigned short* w2base = fw2P + (size_t)lane * 8;

  // per-thread staging geometry (constant): thread owns 8 floats = 1 unit
  const int srow = tid >> 4;          // 0..31
  const int su   = tid & 15;          // unit
  const float* hE_stage = hE_bl + (size_t)tid * 8;
  const int sAoff = srow * 128 + (((su ^ (srow & 7)) & 15) << 3);

  const f32x4 zero4 = {0.f, 0.f, 0.f, 0.f};
  f32x4 xc[3];
  xc[0] = zero4; xc[1] = zero4; xc[2] = zero4;
  f32x4 acc2[2][3];   // G2 result, consumed by epi2 in the NEXT iteration

  // prologue: stage tile 0 (regs -> convert -> swizzled sA[0])
  {
    f32x4 v0 = *(const f32x4*)hE_stage;
    f32x4 v1 = *(const f32x4*)(hE_stage + 4);
    bf16x8 o;
    o[0] = (short)f2bf(v0[0]); o[1] = (short)f2bf(v0[1]);
    o[2] = (short)f2bf(v0[2]); o[3] = (short)f2bf(v0[3]);
    o[4] = (short)f2bf(v1[0]); o[5] = (short)f2bf(v1[1]);
    o[6] = (short)f2bf(v1[2]); o[7] = (short)f2bf(v1[3]);
    *(bf16x8*)((unsigned short*)sMem + sAoff) = o;
  }
  __syncthreads();

  #pragma unroll 1
  for (int it = 0; it < NIT; ++it) {
    const int q = it & 1;
    unsigned short* sAq  = (unsigned short*)(sMem + q * 8192);
    unsigned short* sT1q = (unsigned short*)(sMem + 16384 + q * 24576);

    // ===== G1 mfma (swapped -> C^T): wave owns 48 cols =====
    f32x4 acc1[2][3];
    #pragma unroll
    for (int mt = 0; mt < 2; ++mt)
      #pragma unroll
      for (int nt = 0; nt < 3; ++nt) acc1[mt][nt] = zero4;

    #pragma unroll 2
    for (int ks = 0; ks < 4; ++ks) {
      const int xu = ((ks << 2) + quad) ^ l7;   // swizzled 16B-unit
      bf16x8 afr[2];
      #pragma unroll
      for (int mt = 0; mt < 2; ++mt)
        afr[mt] = *(const bf16x8*)(sAq + ((mt * 16 + lr) << 7) + (xu << 3));
      bf16x8 bfr[3];
      #pragma unroll
      for (int nt = 0; nt < 3; ++nt)
        bfr[nt] = *(const bf16x8*)(w1base +
                      (size_t)(((wave * 3 + nt) * 4 + ks) * 64) * 8);
      __builtin_amdgcn_s_setprio(1);
      #pragma unroll
      for (int mt = 0; mt < 2; ++mt)
        #pragma unroll
        for (int nt = 0; nt < 3; ++nt)
          acc1[mt][nt] = __builtin_amdgcn_mfma_f32_16x16x32_bf16(
              bfr[nt], afr[mt], acc1[mt][nt], 0, 0, 0);
      __builtin_amdgcn_s_setprio(0);
    }

    // stage loads for it+1 (latency hides under epi2+epi1)
    f32x4 s0, s1;
    if (it + 1 < NIT) {
      const float* src = hE_stage + (size_t)(it + 1) * (KT * Hz);
      s0 = *(const f32x4*)src;
      s1 = *(const f32x4*)(src + 4);
    }

    // ===== epi2(it-1): register-only; hides G1 mfma chain =====
    if (it > 0) {
      const int itp = it - 1;
      #pragma unroll
      for (int nt = 0; nt < 3; ++nt) {
        const int n0 = wave * 48 + nt * 16 + quad * 4;
        const f32x4 b2 = *(const f32x4*)(fb2 + n0);
        #pragma unroll
        for (int mt = 0; mt < 2; ++mt) {
          const float* hv =
              hV + ((size_t)b * Lz + itp * KT + mt * 16 + lr) * Fz + n0;
          const f32x4 hvv = *(const f32x4*)hv;
          #pragma unroll
          for (int r = 0; r < 4; ++r)
            xc[nt][r] += gelu_f(acc2[mt][nt][r] + b2[r]) * hvv[r];
        }
      }
    }

    // ===== epi1: bias+gelu -> sT1[q] (swizzled b64 writes) =====
    #pragma unroll
    for (int nt = 0; nt < 3; ++nt) {
      const int n0 = wave * 48 + nt * 16 + quad * 4;
      const f32x4 bias = *(const f32x4*)(fb1 + n0);
      const int so = (((wave * 6 + nt * 2 + (quad >> 1)) ^ l7) << 3)
                     + ((quad & 1) << 2);
      #pragma unroll
      for (int mt = 0; mt < 2; ++mt) {
        short4 o;
        o.x = (short)f2bf(gelu_f(acc1[mt][nt][0] + bias[0]));
        o.y = (short)f2bf(gelu_f(acc1[mt][nt][1] + bias[1]));
        o.z = (short)f2bf(gelu_f(acc1[mt][nt][2] + bias[2]));
        o.w = (short)f2bf(gelu_f(acc1[mt][nt][3] + bias[3]));
        *(short4*)(sT1q + (mt * 16 + lr) * 384 + so) = o;
      }
    }

    // stage conv -> sA[q^1] (disjoint from sA[q] read by G1 this iter)
    if (it + 1 < NIT) {
      bf16x8 o;
      o[0] = (short)f2bf(s0[0]); o[1] = (short)f2bf(s0[1]);
      o[2] = (short)f2bf(s0[2]); o[3] = (short)f2bf(s0[3]);
      o[4] = (short)f2bf(s1[0]); o[5] = (short)f2bf(s1[1]);
      o[6] = (short)f2bf(s1[2]); o[7] = (short)f2bf(s1[3]);
      *(bf16x8*)((unsigned short*)(sMem + (q ^ 1) * 8192) + sAoff) = o;
    }
    __syncthreads();   // publishes sT1[q] for G2 and sA[q^1] for next G1

    // ===== G2 mfma (swapped -> C^T) into acc2 (consumed next iter) =====
    #pragma unroll
    for (int mt = 0; mt < 2; ++mt)
      #pragma unroll
      for (int nt = 0; nt < 3; ++nt) acc2[mt][nt] = zero4;

    #pragma unroll 2
    for (int ks = 0; ks < 12; ++ks) {
      const int xu = ((ks << 2) + quad) ^ l7;
      bf16x8 afr[2];
      #pragma unroll
      for (int mt = 0; mt < 2; ++mt)
        afr[mt] = *(const bf16x8*)(sT1q + (mt * 16 + lr) * 384 + (xu << 3));
      bf16x8 bfr[3];
      #pragma unroll
      for (int nt = 0; nt < 3; ++nt)
        bfr[nt] = *(const bf16x8*)(w2base +
                      (size_t)(((wave * 3 + nt) * 12 + ks) * 64) * 8);
      __builtin_amdgcn_s_setprio(1);
      #pragma unroll
      for (int mt = 0; mt < 2; ++mt)
        #pragma unroll
        for (int nt = 0; nt < 3; ++nt)
          acc2[mt][nt] = __builtin_amdgcn_mfma_f32_16x16x32_bf16(
              bfr[nt], afr[mt], acc2[mt][nt], 0, 0, 0);
      __builtin_amdgcn_s_setprio(0);
    }
  }

  // ===== epi2(NIT-1) =====
  {
    const int itp = NIT - 1;
    #pragma unroll
    for (int nt = 0; nt < 3; ++nt) {
      const int n0 = wave * 48 + nt * 16 + quad * 4;
      const f32x4 b2 = *(const f32x4*)(fb2 + n0);
      #pragma unroll
      for (int mt = 0; mt < 2; ++mt) {
        const float* hv =
            hV + ((size_t)b * Lz + itp * KT + mt * 16 + lr) * Fz + n0;
        const f32x4 hvv = *(const f32x4*)hv;
        #pragma unroll
        for (int r = 0; r < 4; ++r)
          xc[nt][r] += gelu_f(acc2[mt][nt][r] + b2[r]) * hvv[r];
      }
    }
  }

  // reduce xc across the 16 lr lanes -> sXC[n] (aliases sA[0]; reads done)
  #pragma unroll
  for (int nt = 0; nt < 3; ++nt)
    #pragma unroll
    for (int r = 0; r < 4; ++r) {
      float v = xc[nt][r];
      v += __shfl_xor(v, 1);
      v += __shfl_xor(v, 2);
      v += __shfl_xor(v, 4);
      v += __shfl_xor(v, 8);
      if (lr == 0) sXC[wave * 48 + nt * 16 + quad * 4 + r] = v;
    }
  __syncthreads();

  // ---- head MLP (fp32, tiny) ----
  {
    int i = tid & 127;
    int part = tid >> 7;              // 0..3
    float a = 0.f;
    const int f0 = part * 96;
    for (int f = f0; f < f0 + 96; ++f) a += sXC[f] * hw1[f * Hz + i];
    sHp[part * Hz + i] = a;
  }
  __syncthreads();
  if (tid < Hz)
    sH1[tid] = gelu_f(sHp[tid] + sHp[Hz + tid] + sHp[2 * Hz + tid]
                      + sHp[3 * Hz + tid] + hb1[tid]);
  __syncthreads();
  if (tid < 64) {
    float a = hb2[tid];
    for (int i = 0; i < Hz; ++i) a += sH1[i] * hw2[i * 64 + tid];
    sH2[tid] = gelu_f(a);
  }
  __syncthreads();
  if (wave == 0) {
    float v = sH2[lane] * hw3[lane];
    #pragma unroll
    for (int off = 32; off >= 1; off >>= 1) v += __shfl_xor(v, off);
    if (lane == 0) {
      float pred = v + hb3[0];
      atomicAdd(&accbuf[b], pred * mask[b * Lz + l]);
      __threadfence();
      *sLast = (atomicAdd(ctr, 1) == (Bz * Lz - 1));
    }
  }
  __syncthreads();

  // ---- last block: finalize all 4 batches ----
  if (*sLast && wave < Bz) {
    float s = 0.f;
    #pragma unroll
    for (int k = 0; k < Lz / 64; ++k) s += mask[wave * Lz + k * 64 + lane];
    #pragma unroll
    for (int off = 32; off >= 1; off >>= 1) s += __shfl_xor(s, off);
    if (lane == 0) {
      float vl = s < 1.0f ? 1.0f : s;
      float a = atomicAdd(&accbuf[wave], 0.0f);   // coherent read
      out[wave] = a / sqrtf(vl);
    }
  }
}

extern "C" void kernel_launch(void* const* d_in, const int* in_sizes, int n_in,
                              void* d_out, int out_size, void* d_ws, size_t ws_size,
                              hipStream_t stream)
{
  const float* hV   = (const float*)d_in[0];
  const float* hE   = (const float*)d_in[1];
  const float* mask = (const float*)d_in[2];
  const float* fw1  = (const float*)d_in[3];
  const float* fb1  = (const float*)d_in[4];
  const float* fw2  = (const float*)d_in[5];
  const float* fb2  = (const float*)d_in[6];
  const float* hw1  = (const float*)d_in[7];
  const float* hb1  = (const float*)d_in[8];
  const float* hw2  = (const float*)d_in[9];
  const float* hb2  = (const float*)d_in[10];
  const float* hw3  = (const float*)d_in[11];
  const float* hb3  = (const float*)d_in[12];
  float* out = (float*)d_out;

  // ws: [0,64) accbuf; [64,68) ctr; fw1P @1024 (96 KB); fw2P after (288 KB)
  float* accbuf = (float*)d_ws;
  int*   ctr    = (int*)((char*)d_ws + 64);
  unsigned short* fw1P = (unsigned short*)((char*)d_ws + 1024);
  unsigned short* fw2P = fw1P + 24 * 4 * 64 * 8;

  prep_kernel<<<768, 256, 0, stream>>>(fw1, fw2, fw1P, fw2P, accbuf, ctr);
  schnet_main<<<Bz * Lz, 512, 0, stream>>>(hV, hE, mask, fw1P, fb1, fw2P, fb2,
                                           hw1, hb1, hw2, hb2, hw3, hb3,
                                           accbuf, ctr, out);
}